// Round 1
// baseline (1663.513 us; speedup 1.0000x reference)
//
#include <hip/hip_runtime.h>
#include <math.h>

#define P_DIM 1024
#define R_DIM 128
#define B_DIM 8
#define T_DIM 4096
#define NROWS (B_DIM*T_DIM)   // 32768

// ============================================================
// Stage 1: r = t@V_r ; u = (F*t)@V_b * scale ; a = clip(sigmoid(r@W + b))
// One block per 32 rows. 256 threads: c = tid&31 -> cols 4c..4c+3,
// ry = tid>>5 -> rows 4ry..4ry+3.
// ============================================================
__global__ __launch_bounds__(256, 2) void stage1_kernel(
    const float* __restrict__ tin, const float* __restrict__ Fin,
    const float* __restrict__ Vr, const float* __restrict__ Vb,
    const float* __restrict__ Wl, const float* __restrict__ bl,
    float* __restrict__ a_ws, float* __restrict__ u_ws)
{
    __shared__ float tA[32][36];      // stride 36 floats = 144B: 16B-aligned, conflict-free
    __shared__ float tF[32][36];
    __shared__ float Bs[2][32][128];  // V_r / V_b chunks; reused for W chunks
    __shared__ float rS[32][132];     // staged r tile (stride 132 floats = 528B, 16B-aligned)

    const int tid  = threadIdx.x;
    const int c    = tid & 31;
    const int ry   = tid >> 5;
    const int row0 = blockIdx.x * 32;

    float accR[4][4] = {};
    float accU[4][4] = {};

    const int lr = tid >> 3;          // 0..31: tile row for A loads
    const int lk = (tid & 7) << 2;    // 0,4,...,28: k offset for A loads

    for (int k0 = 0; k0 < P_DIM; k0 += 32) {
        __syncthreads();
        // A tiles (t and F*t), 32x32 each
        float4 tv = *(const float4*)(tin + (long)(row0 + lr) * P_DIM + k0 + lk);
        float4 fv = *(const float4*)(Fin + (long)(row0 + lr) * P_DIM + k0 + lk);
        fv.x *= tv.x; fv.y *= tv.y; fv.z *= tv.z; fv.w *= tv.w;
        *(float4*)&tA[lr][lk] = tv;
        *(float4*)&tF[lr][lk] = fv;
        // B tiles: rows k0..k0+31 of V_r / V_b are contiguous 4096-float blocks
#pragma unroll
        for (int i = 0; i < 4; i++) {
            int idx = tid + i * 256;  // float4 index 0..1023
            ((float4*)&Bs[0][0][0])[idx] = ((const float4*)(Vr + (long)k0 * R_DIM))[idx];
            ((float4*)&Bs[1][0][0])[idx] = ((const float4*)(Vb + (long)k0 * R_DIM))[idx];
        }
        __syncthreads();
#pragma unroll
        for (int kk = 0; kk < 32; kk++) {
            float4 vr = *(const float4*)&Bs[0][kk][c * 4];
            float4 vb = *(const float4*)&Bs[1][kk][c * 4];
#pragma unroll
            for (int i = 0; i < 4; i++) {
                float ta = tA[ry * 4 + i][kk];
                float tf = tF[ry * 4 + i][kk];
                accR[i][0] = fmaf(ta, vr.x, accR[i][0]);
                accR[i][1] = fmaf(ta, vr.y, accR[i][1]);
                accR[i][2] = fmaf(ta, vr.z, accR[i][2]);
                accR[i][3] = fmaf(ta, vr.w, accR[i][3]);
                accU[i][0] = fmaf(tf, vb.x, accU[i][0]);
                accU[i][1] = fmaf(tf, vb.y, accU[i][1]);
                accU[i][2] = fmaf(tf, vb.z, accU[i][2]);
                accU[i][3] = fmaf(tf, vb.w, accU[i][3]);
            }
        }
    }

    // stage r into LDS for the 128x128 W_lambda projection
#pragma unroll
    for (int i = 0; i < 4; i++) {
        *(float4*)&rS[ry * 4 + i][c * 4] =
            make_float4(accR[i][0], accR[i][1], accR[i][2], accR[i][3]);
    }

    float4 bl4 = *(const float4*)(bl + c * 4);
    float z[4][4];
#pragma unroll
    for (int i = 0; i < 4; i++) { z[i][0] = bl4.x; z[i][1] = bl4.y; z[i][2] = bl4.z; z[i][3] = bl4.w; }

    for (int kc = 0; kc < R_DIM; kc += 32) {
        __syncthreads();  // covers rS writes (kc==0) and protects Bs reuse
#pragma unroll
        for (int i2 = 0; i2 < 4; i2++) {
            int idx = tid + i2 * 256;
            ((float4*)&Bs[0][0][0])[idx] = ((const float4*)(Wl + (long)kc * R_DIM))[idx];
        }
        __syncthreads();
#pragma unroll
        for (int kk = 0; kk < 32; kk++) {
            float4 w = *(const float4*)&Bs[0][kk][c * 4];
#pragma unroll
            for (int i = 0; i < 4; i++) {
                float rv = rS[ry * 4 + i][kc + kk];
                z[i][0] = fmaf(rv, w.x, z[i][0]);
                z[i][1] = fmaf(rv, w.y, z[i][1]);
                z[i][2] = fmaf(rv, w.z, z[i][2]);
                z[i][3] = fmaf(rv, w.w, z[i][3]);
            }
        }
    }

    const float uscale = 0.08838834764831845f;  // 1/sqrt(128)
#pragma unroll
    for (int i = 0; i < 4; i++) {
        int row = row0 + ry * 4 + i;
        float4 av;
        av.x = fminf(fmaxf(1.f / (1.f + expf(-z[i][0])), 0.01f), 0.995f);
        av.y = fminf(fmaxf(1.f / (1.f + expf(-z[i][1])), 0.01f), 0.995f);
        av.z = fminf(fmaxf(1.f / (1.f + expf(-z[i][2])), 0.01f), 0.995f);
        av.w = fminf(fmaxf(1.f / (1.f + expf(-z[i][3])), 0.01f), 0.995f);
        *(float4*)(a_ws + (long)row * R_DIM + c * 4) = av;
        float4 uv = make_float4(accU[i][0] * uscale, accU[i][1] * uscale,
                                accU[i][2] * uscale, accU[i][3] * uscale);
        *(float4*)(u_ws + (long)row * R_DIM + c * 4) = uv;
    }
}

// ============================================================
// Stage 2: sequential normalized scan. One wave per batch,
// 2 state dims per lane, wave-wide shuffle reduction for RMS.
// ============================================================
__global__ __launch_bounds__(64) void scan_kernel(
    const float* __restrict__ a_ws, const float* __restrict__ u_ws,
    float* __restrict__ s_ws, float* __restrict__ cache_out)
{
    const int b = blockIdx.x;
    const int lane = threadIdx.x;
    const long base = (long)b * T_DIM * R_DIM + lane * 2;

    float2 s = make_float2(0.f, 0.f);
    float2 av = *(const float2*)(a_ws + base);
    float2 uv = *(const float2*)(u_ws + base);

    for (int i = 0; i < T_DIM; i++) {
        int inext = (i + 1 < T_DIM) ? i + 1 : i;
        float2 an = *(const float2*)(a_ws + base + (long)inext * R_DIM);
        float2 un = *(const float2*)(u_ws + base + (long)inext * R_DIM);

        float2 v;
        v.x = fmaf(av.x, s.x, uv.x);
        v.y = fmaf(av.y, s.y, uv.y);
        float sq = v.x * v.x + v.y * v.y;
#pragma unroll
        for (int m = 1; m < 64; m <<= 1) sq += __shfl_xor(sq, m, 64);
        float inv = rsqrtf(fmaf(sq, 0.0078125f, 1e-6f));  // 1/sqrt(mean+eps)
        s.x = v.x * inv;
        s.y = v.y * inv;
        *(float2*)(s_ws + base + (long)i * R_DIM) = s;

        av = an; uv = un;
    }
    *(float2*)(cache_out + b * R_DIM + lane * 2) = s;
}

// ============================================================
// Stage 3: t_tilde = s @ V_o + t.  Block = 16 rows x 256 cols.
// ============================================================
__global__ __launch_bounds__(256, 2) void stage3_kernel(
    const float* __restrict__ s_ws, const float* __restrict__ Vo,
    const float* __restrict__ tin, float* __restrict__ out)
{
    __shared__ float sS[16][128];
    __shared__ float VoS[32][256];

    const int tid = threadIdx.x;
    const int cb = blockIdx.x & 3;
    const int rb = blockIdx.x >> 2;
    const int row0 = rb * 16;
    const int col0 = cb * 256;
    const int tx = tid & 63;   // col quad: cols col0 + 4tx..
    const int ty = tid >> 6;   // rows ty*4..ty*4+3 (wave-uniform -> broadcast reads)

    float acc[4][4] = {};

#pragma unroll
    for (int i = 0; i < 2; i++) {
        int idx = tid + i * 256;  // float4 idx 0..511 covering 16x128
        ((float4*)&sS[0][0])[idx] = *(const float4*)(s_ws + (long)row0 * R_DIM + idx * 4);
    }

    for (int k0 = 0; k0 < R_DIM; k0 += 32) {
        __syncthreads();
#pragma unroll
        for (int i = 0; i < 8; i++) {
            int idx = tid + i * 256;    // float4 idx 0..2047 covering 32x256
            int r = idx >> 6;
            int cq = idx & 63;
            *(float4*)&VoS[r][cq * 4] =
                *(const float4*)(Vo + (long)(k0 + r) * P_DIM + col0 + cq * 4);
        }
        __syncthreads();
#pragma unroll
        for (int kk = 0; kk < 32; kk++) {
            float4 w = *(const float4*)&VoS[kk][tx * 4];
#pragma unroll
            for (int i = 0; i < 4; i++) {
                float sv = sS[ty * 4 + i][k0 + kk];
                acc[i][0] = fmaf(sv, w.x, acc[i][0]);
                acc[i][1] = fmaf(sv, w.y, acc[i][1]);
                acc[i][2] = fmaf(sv, w.z, acc[i][2]);
                acc[i][3] = fmaf(sv, w.w, acc[i][3]);
            }
        }
    }

#pragma unroll
    for (int i = 0; i < 4; i++) {
        int row = row0 + ty * 4 + i;
        float4 tv = *(const float4*)(tin + (long)row * P_DIM + col0 + tx * 4);
        float4 o = make_float4(acc[i][0] + tv.x, acc[i][1] + tv.y,
                               acc[i][2] + tv.z, acc[i][3] + tv.w);
        *(float4*)(out + (long)row * P_DIM + col0 + tx * 4) = o;
    }
}

extern "C" void kernel_launch(void* const* d_in, const int* in_sizes, int n_in,
                              void* d_out, int out_size, void* d_ws, size_t ws_size,
                              hipStream_t stream) {
    const float* t  = (const float*)d_in[0];
    const float* F  = (const float*)d_in[1];
    const float* Vr = (const float*)d_in[2];
    const float* Vb = (const float*)d_in[3];
    const float* Vo = (const float*)d_in[4];
    const float* Wl = (const float*)d_in[5];
    const float* bl = (const float*)d_in[6];
    float* out = (float*)d_out;

    float* a_ws = (float*)d_ws;                      // 32768*128 f32 = 16 MB
    float* u_ws = a_ws + (long)NROWS * R_DIM;        // 16 MB
    float* s_ws = u_ws + (long)NROWS * R_DIM;        // 16 MB

    hipLaunchKernelGGL(stage1_kernel, dim3(NROWS / 32), dim3(256), 0, stream,
                       t, F, Vr, Vb, Wl, bl, a_ws, u_ws);
    hipLaunchKernelGGL(scan_kernel, dim3(B_DIM), dim3(64), 0, stream,
                       a_ws, u_ws, s_ws, out + (long)NROWS * P_DIM);
    hipLaunchKernelGGL(stage3_kernel, dim3((NROWS / 16) * 4), dim3(256), 0, stream,
                       s_ws, Vo, t, out);
}

// Round 3
// 1112.987 us; speedup vs baseline: 1.4946x; 1.4946x over previous
//
#include <hip/hip_runtime.h>
#include <math.h>

#define P_DIM 1024
#define R_DIM 128
#define B_DIM 8
#define T_DIM 4096
#define NROWS (B_DIM*T_DIM)   // 32768

// ============================================================
// Stage 1: r = t@V_r ; u = (F*t)@V_b * scale ; a = clip(sigmoid(r@W + b))
// ============================================================
__global__ __launch_bounds__(256, 2) void stage1_kernel(
    const float* __restrict__ tin, const float* __restrict__ Fin,
    const float* __restrict__ Vr, const float* __restrict__ Vb,
    const float* __restrict__ Wl, const float* __restrict__ bl,
    float* __restrict__ a_ws, float* __restrict__ u_ws)
{
    __shared__ float tA[32][36];
    __shared__ float tF[32][36];
    __shared__ float Bs[2][32][128];
    __shared__ float rS[32][132];

    const int tid  = threadIdx.x;
    const int c    = tid & 31;
    const int ry   = tid >> 5;
    const int row0 = blockIdx.x * 32;

    float accR[4][4] = {};
    float accU[4][4] = {};

    const int lr = tid >> 3;
    const int lk = (tid & 7) << 2;

    for (int k0 = 0; k0 < P_DIM; k0 += 32) {
        __syncthreads();
        float4 tv = *(const float4*)(tin + (long)(row0 + lr) * P_DIM + k0 + lk);
        float4 fv = *(const float4*)(Fin + (long)(row0 + lr) * P_DIM + k0 + lk);
        fv.x *= tv.x; fv.y *= tv.y; fv.z *= tv.z; fv.w *= tv.w;
        *(float4*)&tA[lr][lk] = tv;
        *(float4*)&tF[lr][lk] = fv;
#pragma unroll
        for (int i = 0; i < 4; i++) {
            int idx = tid + i * 256;
            ((float4*)&Bs[0][0][0])[idx] = ((const float4*)(Vr + (long)k0 * R_DIM))[idx];
            ((float4*)&Bs[1][0][0])[idx] = ((const float4*)(Vb + (long)k0 * R_DIM))[idx];
        }
        __syncthreads();
#pragma unroll
        for (int kk = 0; kk < 32; kk++) {
            float4 vr = *(const float4*)&Bs[0][kk][c * 4];
            float4 vb = *(const float4*)&Bs[1][kk][c * 4];
#pragma unroll
            for (int i = 0; i < 4; i++) {
                float ta = tA[ry * 4 + i][kk];
                float tf = tF[ry * 4 + i][kk];
                accR[i][0] = fmaf(ta, vr.x, accR[i][0]);
                accR[i][1] = fmaf(ta, vr.y, accR[i][1]);
                accR[i][2] = fmaf(ta, vr.z, accR[i][2]);
                accR[i][3] = fmaf(ta, vr.w, accR[i][3]);
                accU[i][0] = fmaf(tf, vb.x, accU[i][0]);
                accU[i][1] = fmaf(tf, vb.y, accU[i][1]);
                accU[i][2] = fmaf(tf, vb.z, accU[i][2]);
                accU[i][3] = fmaf(tf, vb.w, accU[i][3]);
            }
        }
    }

#pragma unroll
    for (int i = 0; i < 4; i++) {
        *(float4*)&rS[ry * 4 + i][c * 4] =
            make_float4(accR[i][0], accR[i][1], accR[i][2], accR[i][3]);
    }

    float4 bl4 = *(const float4*)(bl + c * 4);
    float z[4][4];
#pragma unroll
    for (int i = 0; i < 4; i++) { z[i][0] = bl4.x; z[i][1] = bl4.y; z[i][2] = bl4.z; z[i][3] = bl4.w; }

    for (int kc = 0; kc < R_DIM; kc += 32) {
        __syncthreads();
#pragma unroll
        for (int i2 = 0; i2 < 4; i2++) {
            int idx = tid + i2 * 256;
            ((float4*)&Bs[0][0][0])[idx] = ((const float4*)(Wl + (long)kc * R_DIM))[idx];
        }
        __syncthreads();
#pragma unroll
        for (int kk = 0; kk < 32; kk++) {
            float4 w = *(const float4*)&Bs[0][kk][c * 4];
#pragma unroll
            for (int i = 0; i < 4; i++) {
                float rv = rS[ry * 4 + i][kc + kk];
                z[i][0] = fmaf(rv, w.x, z[i][0]);
                z[i][1] = fmaf(rv, w.y, z[i][1]);
                z[i][2] = fmaf(rv, w.z, z[i][2]);
                z[i][3] = fmaf(rv, w.w, z[i][3]);
            }
        }
    }

    const float uscale = 0.08838834764831845f;  // 1/sqrt(128)
#pragma unroll
    for (int i = 0; i < 4; i++) {
        int row = row0 + ry * 4 + i;
        float4 av;
        av.x = fminf(fmaxf(1.f / (1.f + expf(-z[i][0])), 0.01f), 0.995f);
        av.y = fminf(fmaxf(1.f / (1.f + expf(-z[i][1])), 0.01f), 0.995f);
        av.z = fminf(fmaxf(1.f / (1.f + expf(-z[i][2])), 0.01f), 0.995f);
        av.w = fminf(fmaxf(1.f / (1.f + expf(-z[i][3])), 0.01f), 0.995f);
        *(float4*)(a_ws + (long)row * R_DIM + c * 4) = av;
        float4 uv = make_float4(accU[i][0] * uscale, accU[i][1] * uscale,
                                accU[i][2] * uscale, accU[i][3] * uscale);
        *(float4*)(u_ws + (long)row * R_DIM + c * 4) = uv;
    }
}

// ============================================================
// Stage 2: sequential normalized scan.
// DPP butterfly reduction (VALU-only, no LDS round-trips) +
// 16-step register prefetch to hide L3/HBM load latency.
// ============================================================
template <int CTRL, int ROW_MASK>
__device__ __forceinline__ float dpp_add(float x) {
    int xi = __float_as_int(x);
    int yi = __builtin_amdgcn_update_dpp(0, xi, CTRL, ROW_MASK, 0xf, false);
    return x + __int_as_float(yi);
}

__device__ __forceinline__ float wave64_sum(float x) {
    x = dpp_add<0xB1,  0xf>(x);  // quad_perm [1,0,3,2]  : xor 1
    x = dpp_add<0x4E,  0xf>(x);  // quad_perm [2,3,0,1]  : xor 2
    x = dpp_add<0x141, 0xf>(x);  // row_half_mirror      : xor 4
    x = dpp_add<0x140, 0xf>(x);  // row_mirror           : xor 8
    x = dpp_add<0x142, 0xa>(x);  // row_bcast:15 -> rows 1,3
    x = dpp_add<0x143, 0xc>(x);  // row_bcast:31 -> rows 2,3; lane63 = total
    return __int_as_float(__builtin_amdgcn_readlane(__float_as_int(x), 63));
}

#define PF 16   // prefetch depth: ~16 steps * ~65cyc > 900cyc HBM latency

__global__ __launch_bounds__(64) void scan_kernel(
    const float* __restrict__ a_ws, const float* __restrict__ u_ws,
    float* __restrict__ s_ws, float* __restrict__ cache_out)
{
    const int b = blockIdx.x;
    const int lane = threadIdx.x;
    const long base = (long)b * T_DIM * R_DIM + lane * 2;

    float2 ab[PF], ub[PF];
#pragma unroll
    for (int j = 0; j < PF; j++) {
        ab[j] = *(const float2*)(a_ws + base + (long)j * R_DIM);
        ub[j] = *(const float2*)(u_ws + base + (long)j * R_DIM);
    }

    float2 s = make_float2(0.f, 0.f);

    for (int i0 = 0; i0 < T_DIM; i0 += PF) {
#pragma unroll
        for (int j = 0; j < PF; j++) {
            const int i = i0 + j;
            float2 av = ab[j];
            float2 uv = ub[j];
            if (i0 + PF < T_DIM) {   // uniform branch: prefetch step i+PF
                ab[j] = *(const float2*)(a_ws + base + (long)(i + PF) * R_DIM);
                ub[j] = *(const float2*)(u_ws + base + (long)(i + PF) * R_DIM);
            }
            float2 v;
            v.x = fmaf(av.x, s.x, uv.x);
            v.y = fmaf(av.y, s.y, uv.y);
            float sq = fmaf(v.x, v.x, v.y * v.y);
            float total = wave64_sum(sq);
            float inv = rsqrtf(fmaf(total, 0.0078125f, 1e-6f)); // mean over 128 + eps
            s.x = v.x * inv;
            s.y = v.y * inv;
            *(float2*)(s_ws + base + (long)i * R_DIM) = s;
        }
    }
    *(float2*)(cache_out + b * R_DIM + lane * 2) = s;
}

// ============================================================
// Stage 3: t_tilde = s @ V_o + t.
// ============================================================
__global__ __launch_bounds__(256, 2) void stage3_kernel(
    const float* __restrict__ s_ws, const float* __restrict__ Vo,
    const float* __restrict__ tin, float* __restrict__ out)
{
    __shared__ float sS[16][128];
    __shared__ float VoS[32][256];

    const int tid = threadIdx.x;
    const int cb = blockIdx.x & 3;
    const int rb = blockIdx.x >> 2;
    const int row0 = rb * 16;
    const int col0 = cb * 256;
    const int tx = tid & 63;
    const int ty = tid >> 6;

    float acc[4][4] = {};

#pragma unroll
    for (int i = 0; i < 2; i++) {
        int idx = tid + i * 256;
        ((float4*)&sS[0][0])[idx] = *(const float4*)(s_ws + (long)row0 * R_DIM + idx * 4);
    }

    for (int k0 = 0; k0 < R_DIM; k0 += 32) {
        __syncthreads();
#pragma unroll
        for (int i = 0; i < 8; i++) {
            int idx = tid + i * 256;
            int r = idx >> 6;
            int cq = idx & 63;
            *(float4*)&VoS[r][cq * 4] =
                *(const float4*)(Vo + (long)(k0 + r) * P_DIM + col0 + cq * 4);
        }
        __syncthreads();
#pragma unroll
        for (int kk = 0; kk < 32; kk++) {
            float4 w = *(const float4*)&VoS[kk][tx * 4];
#pragma unroll
            for (int i = 0; i < 4; i++) {
                float sv = sS[ty * 4 + i][k0 + kk];
                acc[i][0] = fmaf(sv, w.x, acc[i][0]);
                acc[i][1] = fmaf(sv, w.y, acc[i][1]);
                acc[i][2] = fmaf(sv, w.z, acc[i][2]);
                acc[i][3] = fmaf(sv, w.w, acc[i][3]);
            }
        }
    }

#pragma unroll
    for (int i = 0; i < 4; i++) {
        int row = row0 + ty * 4 + i;
        float4 tv = *(const float4*)(tin + (long)row * P_DIM + col0 + tx * 4);
        float4 o = make_float4(acc[i][0] + tv.x, acc[i][1] + tv.y,
                               acc[i][2] + tv.z, acc[i][3] + tv.w);
        *(float4*)(out + (long)row * P_DIM + col0 + tx * 4) = o;
    }
}

extern "C" void kernel_launch(void* const* d_in, const int* in_sizes, int n_in,
                              void* d_out, int out_size, void* d_ws, size_t ws_size,
                              hipStream_t stream) {
    const float* t  = (const float*)d_in[0];
    const float* F  = (const float*)d_in[1];
    const float* Vr = (const float*)d_in[2];
    const float* Vb = (const float*)d_in[3];
    const float* Vo = (const float*)d_in[4];
    const float* Wl = (const float*)d_in[5];
    const float* bl = (const float*)d_in[6];
    float* out = (float*)d_out;

    float* a_ws = (float*)d_ws;                      // 16 MB
    float* u_ws = a_ws + (long)NROWS * R_DIM;        // 16 MB
    float* s_ws = u_ws + (long)NROWS * R_DIM;        // 16 MB

    hipLaunchKernelGGL(stage1_kernel, dim3(NROWS / 32), dim3(256), 0, stream,
                       t, F, Vr, Vb, Wl, bl, a_ws, u_ws);
    hipLaunchKernelGGL(scan_kernel, dim3(B_DIM), dim3(64), 0, stream,
                       a_ws, u_ws, s_ws, out + (long)NROWS * P_DIM);
    hipLaunchKernelGGL(stage3_kernel, dim3((NROWS / 16) * 4), dim3(256), 0, stream,
                       s_ws, Vo, t, out);
}